// Round 4
// baseline (106.947 us; speedup 1.0000x reference)
//
#include <hip/hip_runtime.h>

#define T_LEN   1048576
#define CHUNK   16
#define WARM    448                          // rho^448 ~ 1.4e-2 contraction of start-guess error
#define SBLOCK  256
#define OUTS_PER_BLOCK (SBLOCK * CHUNK)      // 4096
#define SGRID   (T_LEN / OUTS_PER_BLOCK)     // 256 blocks -> 1/CU, all co-resident (>=8/CU capacity)
#define WIN     (WARM + OUTS_PER_BLOCK)      // 4544 floats per block window
#define WIN4    (WIN / 4)                    // 1136 float4
#define LDS_DW  (WIN + (WIN / 64) * 4)       // +4 dwords pad per 64 -> 4828 dwords (19.3 KB)
#define FLAG_MAGIC 0x13572468u               // != 0xAAAAAAAA poison

// ---------------- Recurrence step (11 VALU, shared t = u^2/h) ----------------------
// u = y - lam*h;  r = 1/h;  t = u*u*r  (= innov+1)
//   q' = (c0 - vphi)          + rho*q + cv2*u          + vphi*t
//   h' = ((1-phi)(c0-vphi)-alpha) + E*q + B*u + phi*h  + A*t
// c0=omega(1-rho), cv2=-2*gam2*vphi, c1=-2*gam1*alpha,
// A=alpha+(1-phi)vphi, B=c1+(1-phi)cv2, E=(1-phi)rho
struct ChnP { float lam, DA, E, B, phi, A, cV, rho, cv2, vphi; };

__device__ __forceinline__ void chn_step(float yv, float& h, float& q, const ChnP& P) {
    float u  = fmaf(-P.lam, h, yv);
    float r  = __builtin_amdgcn_rcpf(h);     // parallel with u
    float hl = fmaf(P.E, q, P.DA);
    float ql = fmaf(P.rho, q, P.cV);
    float u2 = u * u;
    hl = fmaf(P.B, u, hl);
    ql = fmaf(P.cv2, u, ql);
    hl = fmaf(P.phi, h, hl);
    float t  = u2 * r;
    h = fmaf(P.A, t, hl);
    q = fmaf(P.vphi, t, ql);
}

__device__ __forceinline__ void chn_step4(const float4& v, float& h, float& q, const ChnP& P) {
    chn_step(v.x, h, q, P);
    chn_step(v.y, h, q, P);
    chn_step(v.z, h, q, P);
    chn_step(v.w, h, q, P);
}

// padded LDS index: +4 dwords per 64 (keeps 16B alignment of 4-aligned d)
__device__ __forceinline__ float4 lds_r4(const float* b, int d) {
    return *(const float4*)&b[d + ((d >> 6) << 2)];
}
__device__ __forceinline__ void lds_w4(float* b, int d, float4 v) {
    *(float4*)&b[d + ((d >> 6) << 2)] = v;
}

// ---------------- Fused kernel: stage -> var partial -> publish/spin -> scan -------
__global__ __launch_bounds__(SBLOCK, 1)
void chn_fused_kernel(const float* __restrict__ y, float* __restrict__ out,
                      double* __restrict__ ps, double* __restrict__ ps2,
                      unsigned* __restrict__ flags,
                      const float* __restrict__ p_omega, const float* __restrict__ p_alpha,
                      const float* __restrict__ p_phi,   const float* __restrict__ p_lam,
                      const float* __restrict__ p_gam1,  const float* __restrict__ p_gam2,
                      const float* __restrict__ p_vphi,  const float* __restrict__ p_rho) {
    __shared__ __align__(16) float ybuf[LDS_DW];

    const int B0    = blockIdx.x * OUTS_PER_BLOCK;
    const int gbase = (blockIdx.x == 0) ? 0 : (B0 - WARM);

    // ---- stage window into LDS, coalesced global float4 reads (y read ONCE) ----
    {
        const float4* g4 = (const float4*)(y + gbase);
        for (int i = threadIdx.x; i < WIN4; i += SBLOCK) {
            lds_w4(ybuf, 4 * i, g4[i]);
        }
    }

    // ---- params + constants (overlaps with staging loads) ----
    const float omega = *p_omega, alpha = *p_alpha, phi = *p_phi, lam = *p_lam;
    const float gam1 = *p_gam1, gam2 = *p_gam2, vphi = *p_vphi, rho = *p_rho;
    const float onemphi = 1.0f - phi;
    const float c0  = omega * (1.0f - rho);
    const float cv2 = -2.0f * gam2 * vphi;
    const float c1  = -2.0f * gam1 * alpha;
    ChnP P;
    P.lam = lam; P.rho = rho; P.cv2 = cv2; P.vphi = vphi; P.phi = phi;
    P.A  = fmaf(onemphi, vphi, alpha);
    P.B  = fmaf(onemphi, cv2, c1);
    P.E  = onemphi * rho;
    P.DA = onemphi * c0 - P.A;
    P.cV = c0 - vphi;

    __syncthreads();

    // ---- fp64 variance partial over this block's OWN slice y[B0 .. B0+4095] (from LDS) ----
    {
        const int voff = (blockIdx.x == 0) ? 0 : WARM;   // slice start inside window
        double s = 0.0, s2 = 0.0;
        #pragma unroll
        for (int k = 0; k < 4; ++k) {
            float4 v = lds_r4(ybuf, voff + 4 * threadIdx.x + 1024 * k);
            double a = v.x, b = v.y, c = v.z, d = v.w;
            s  += (a + b) + (c + d);
            s2 += (a * a + b * b) + (c * c + d * d);
        }
        #pragma unroll
        for (int off = 32; off >= 1; off >>= 1) {
            s  += __shfl_down(s,  off, 64);
            s2 += __shfl_down(s2, off, 64);
        }
        __shared__ double lsum[4], lsq[4];
        int wv = threadIdx.x >> 6;
        if ((threadIdx.x & 63) == 0) { lsum[wv] = s; lsq[wv] = s2; }
        __syncthreads();
        if (threadIdx.x == 0) {
            double ts  = (lsum[0] + lsum[1]) + (lsum[2] + lsum[3]);
            double ts2 = (lsq[0]  + lsq[1])  + (lsq[2]  + lsq[3]);
            // device-scope publication (bypasses non-coherent per-XCD L2)
            __hip_atomic_store(&ps[blockIdx.x],  ts,  __ATOMIC_RELAXED, __HIP_MEMORY_SCOPE_AGENT);
            __hip_atomic_store(&ps2[blockIdx.x], ts2, __ATOMIC_RELAXED, __HIP_MEMORY_SCOPE_AGENT);
            __hip_atomic_store(&flags[blockIdx.x], FLAG_MAGIC, __ATOMIC_RELEASE, __HIP_MEMORY_SCOPE_AGENT);
        }
    }

    // ---- spin: thread t waits for block t's flag; barrier => all 256 published ----
    // Safe: all 256 blocks are co-resident (1 launched/CU, >=8/CU capacity) -> no deadlock.
    while (__hip_atomic_load(&flags[threadIdx.x], __ATOMIC_ACQUIRE, __HIP_MEMORY_SCOPE_AGENT)
           != FLAG_MAGIC) {
        __builtin_amdgcn_s_sleep(1);
    }
    __syncthreads();

    // ---- wave-redundant reduce of the 256 partials ----
    int lane = threadIdx.x & 63;
    double s = 0.0, s2 = 0.0;
    #pragma unroll
    for (int k = 0; k < 4; ++k) {
        s  += __hip_atomic_load(&ps[lane + 64 * k],  __ATOMIC_RELAXED, __HIP_MEMORY_SCOPE_AGENT);
        s2 += __hip_atomic_load(&ps2[lane + 64 * k], __ATOMIC_RELAXED, __HIP_MEMORY_SCOPE_AGENT);
    }
    #pragma unroll
    for (int off = 32; off >= 1; off >>= 1) {
        s  += __shfl_xor(s,  off, 64);
        s2 += __shfl_xor(s2, off, 64);
    }
    const double inv_t = 1.0 / (double)T_LEN;
    double mean = s * inv_t;
    const float var = (float)(s2 * inv_t - mean * mean);

    // ---- chunked scan with contractive warm-up, all reads from LDS ----
    const int t0 = B0 + threadIdx.x * CHUNK;
    float h = var, q = var;
    float4* out4 = (float4*)(out + t0);

    if (blockIdx.x != 0) {
        const int dw = threadIdx.x * CHUNK;      // warm start dword in LDS
        float4 a = lds_r4(ybuf, dw + 0);
        float4 b = lds_r4(ybuf, dw + 4);
        #pragma unroll 2
        for (int f = 0; f < WARM / 4; f += 2) {
            float4 na = lds_r4(ybuf, dw + 4 * (f + 2));  // last iter prefetches y[t0..t0+7]
            float4 nb = lds_r4(ybuf, dw + 4 * (f + 3));
            chn_step4(a, h, q, P);
            chn_step4(b, h, q, P);
            a = na; b = nb;
        }
        float4 c = lds_r4(ybuf, dw + WARM + 8);
        float4 d = lds_r4(ybuf, dw + WARM + 12);
        float4 o;
        o.x = h; chn_step(a.x, h, q, P);
        o.y = h; chn_step(a.y, h, q, P);
        o.z = h; chn_step(a.z, h, q, P);
        o.w = h; chn_step(a.w, h, q, P);
        out4[0] = o;
        o.x = h; chn_step(b.x, h, q, P);
        o.y = h; chn_step(b.y, h, q, P);
        o.z = h; chn_step(b.z, h, q, P);
        o.w = h; chn_step(b.w, h, q, P);
        out4[1] = o;
        o.x = h; chn_step(c.x, h, q, P);
        o.y = h; chn_step(c.y, h, q, P);
        o.z = h; chn_step(c.z, h, q, P);
        o.w = h; chn_step(c.w, h, q, P);
        out4[2] = o;
        o.x = h; chn_step(d.x, h, q, P);
        o.y = h; chn_step(d.y, h, q, P);
        o.z = h; chn_step(d.z, h, q, P);
        o.w = h; chn_step(d.w, h, q, P);
        out4[3] = o;
    } else {
        // block 0: exact ramp from t=0 (gbase == 0, LDS dword == global index)
        const int nW = (t0 < WARM) ? t0 : WARM;  // multiple of 16
        const int d0 = t0 - nW;
        for (int f = 0; f < nW / 4; ++f) {
            float4 v = lds_r4(ybuf, d0 + 4 * f);
            chn_step4(v, h, q, P);
        }
        #pragma unroll
        for (int j = 0; j < CHUNK / 4; ++j) {
            float4 v = lds_r4(ybuf, t0 + 4 * j);
            float4 o;
            o.x = h; chn_step(v.x, h, q, P);
            o.y = h; chn_step(v.y, h, q, P);
            o.z = h; chn_step(v.z, h, q, P);
            o.w = h; chn_step(v.w, h, q, P);
            out4[j] = o;
        }
    }
}

extern "C" void kernel_launch(void* const* d_in, const int* in_sizes, int n_in,
                              void* d_out, int out_size, void* d_ws, size_t ws_size,
                              hipStream_t stream) {
    const float* y = (const float*)d_in[0];
    float* out = (float*)d_out;
    // ws layout: ps[256] fp64 | ps2[256] fp64 | flags[256] u32  (poisoned 0xAA each launch)
    double*   ps    = (double*)d_ws;
    double*   ps2   = (double*)((char*)d_ws + 2048);
    unsigned* flags = (unsigned*)((char*)d_ws + 4096);

    chn_fused_kernel<<<SGRID, SBLOCK, 0, stream>>>(
        y, out, ps, ps2, flags,
        (const float*)d_in[1], (const float*)d_in[2], (const float*)d_in[3],
        (const float*)d_in[4], (const float*)d_in[5], (const float*)d_in[6],
        (const float*)d_in[7], (const float*)d_in[8]);
}

// Round 5
// 90.175 us; speedup vs baseline: 1.1860x; 1.1860x over previous
//
#include <hip/hip_runtime.h>

#define T_LEN   1048576
#define CHUNK   8                            // 8 outputs/thread -> 2 waves/SIMD for latency hiding
#define WARM    384                          // rho^384 ~ 2.6e-2; adds ~1.3e-6 truncation (thr 7.5e-6)
#define SBLOCK  256
#define OUTS_PER_BLOCK (SBLOCK * CHUNK)      // 2048
#define SGRID   (T_LEN / OUTS_PER_BLOCK)     // 512 blocks -> 2 blocks/CU
#define WIN     (WARM + OUTS_PER_BLOCK)      // 2432 floats per block window
#define WIN4    (WIN / 4)                    // 608 float4
#define LDS_DW  (WIN + (WIN / 64) * 4)       // pad +4 dwords per 64 -> 2584 dwords (10.3 KB)
#define RGRID   256

typedef float v2f __attribute__((ext_vector_type(2)));

// ---------------- Kernel A: per-block fp64 partial sums (no atomics) --------------
__global__ __launch_bounds__(256)
void var_partials_kernel(const float* __restrict__ y, double2* __restrict__ ws) {
    int tid = blockIdx.x * blockDim.x + threadIdx.x;
    const float4* y4 = (const float4*)y;
    const int stride = RGRID * 256;          // 65536
    float4 v0 = y4[tid];
    float4 v1 = y4[tid + stride];
    float4 v2 = y4[tid + 2 * stride];
    float4 v3 = y4[tid + 3 * stride];
    double s = 0.0, s2 = 0.0;
    #define ACC(v) { double a=(v).x,b=(v).y,c=(v).z,d=(v).w; s += (a+b)+(c+d); s2 += (a*a+b*b)+(c*c+d*d); }
    ACC(v0) ACC(v1) ACC(v2) ACC(v3)
    #undef ACC
    for (int off = 32; off >= 1; off >>= 1) {
        s  += __shfl_down(s,  off, 64);
        s2 += __shfl_down(s2, off, 64);
    }
    __shared__ double lsum[4], lsq[4];
    int lane = threadIdx.x & 63, wv = threadIdx.x >> 6;
    if (lane == 0) { lsum[wv] = s; lsq[wv] = s2; }
    __syncthreads();
    if (threadIdx.x == 0) {
        double2 o;
        o.x = (lsum[0] + lsum[1]) + (lsum[2] + lsum[3]);
        o.y = (lsq[0]  + lsq[1])  + (lsq[2]  + lsq[3]);
        ws[blockIdx.x] = o;
    }
}

// ---------------- Recurrence step: packed h/q paths (v_pk_fma_f32) -----------------
// u = y - lam*h;  r = 1/h;  t = u*u*r  (= innov+1)
//   [h'] = [DA]  + [E  ]q + [B  ]u + [phi]h + [A   ]t
//   [q'] = [cV]  + [rho]q + [cv2]u + [0  ]h + [vphi]t
struct ChnP {
    float lam;
    v2f DC;   // {DA, cV}
    v2f EC;   // {E, rho}
    v2f BC;   // {B, cv2}
    v2f PH;   // {phi, 0}
    v2f AV;   // {A, vphi}
};

__device__ __forceinline__ void chn_step(float yv, float& h, float& q, const ChnP& P) {
    float u  = fmaf(-P.lam, h, yv);
    float r  = __builtin_amdgcn_rcpf(h);     // trans pipe, parallel with u
    v2f acc  = __builtin_elementwise_fma(P.EC, (v2f){q, q}, P.DC);
    float u2 = u * u;
    acc      = __builtin_elementwise_fma(P.BC, (v2f){u, u}, acc);
    acc      = __builtin_elementwise_fma(P.PH, (v2f){h, h}, acc);  // q-lane: +0*h
    float t  = u2 * r;
    acc      = __builtin_elementwise_fma(P.AV, (v2f){t, t}, acc);
    h = acc.x;
    q = acc.y;
}

__device__ __forceinline__ void chn_step4(const float4& v, float& h, float& q, const ChnP& P) {
    chn_step(v.x, h, q, P);
    chn_step(v.y, h, q, P);
    chn_step(v.z, h, q, P);
    chn_step(v.w, h, q, P);
}

// padded LDS index: +4 dwords per 64 (keeps 16B alignment of 4-aligned d)
__device__ __forceinline__ float4 lds_r4(const float* b, int d) {
    return *(const float4*)&b[d + ((d >> 6) << 2)];
}
__device__ __forceinline__ void lds_w4(float* b, int d, float4 v) {
    *(float4*)&b[d + ((d >> 6) << 2)] = v;
}

// ---------------- Kernel B: LDS-staged chunked scan, 2 waves/SIMD ------------------
__global__ __launch_bounds__(SBLOCK)
void chn_scan_kernel(const float* __restrict__ y, float* __restrict__ out,
                     const double2* __restrict__ ws,
                     const float* __restrict__ p_omega, const float* __restrict__ p_alpha,
                     const float* __restrict__ p_phi,   const float* __restrict__ p_lam,
                     const float* __restrict__ p_gam1,  const float* __restrict__ p_gam2,
                     const float* __restrict__ p_vphi,  const float* __restrict__ p_rho) {
    __shared__ __align__(16) float ybuf[LDS_DW];

    const int B0    = blockIdx.x * OUTS_PER_BLOCK;
    const int gbase = (blockIdx.x == 0) ? 0 : (B0 - WARM);

    // ---- stage window into LDS, coalesced global float4 reads ----
    {
        const float4* g4 = (const float4*)(y + gbase);
        for (int i = threadIdx.x; i < WIN4; i += SBLOCK) {
            lds_w4(ybuf, 4 * i, g4[i]);
        }
    }

    // ---- params + constants (overlaps with staging loads) ----
    const float omega = *p_omega, alpha = *p_alpha, phi = *p_phi, lam = *p_lam;
    const float gam1 = *p_gam1, gam2 = *p_gam2, vphi = *p_vphi, rho = *p_rho;
    const float onemphi = 1.0f - phi;
    const float c0  = omega * (1.0f - rho);
    const float cv2 = -2.0f * gam2 * vphi;
    const float c1  = -2.0f * gam1 * alpha;
    const float A   = fmaf(onemphi, vphi, alpha);
    const float B   = fmaf(onemphi, cv2, c1);
    const float E   = onemphi * rho;
    ChnP P;
    P.lam = lam;
    P.DC  = (v2f){onemphi * c0 - A, c0 - vphi};
    P.EC  = (v2f){E, rho};
    P.BC  = (v2f){B, cv2};
    P.PH  = (v2f){phi, 0.0f};
    P.AV  = (v2f){A, vphi};

    // ---- variance: wave-redundant reduce of 256 double2 partials ----
    int lane = threadIdx.x & 63;
    double s = 0.0, s2 = 0.0;
    #pragma unroll
    for (int k = 0; k < 4; ++k) {
        double2 v = ws[lane + 64 * k];
        s += v.x; s2 += v.y;
    }
    #pragma unroll
    for (int off = 32; off >= 1; off >>= 1) {
        s  += __shfl_xor(s,  off, 64);
        s2 += __shfl_xor(s2, off, 64);
    }
    const double inv_t = 1.0 / (double)T_LEN;
    double mean = s * inv_t;
    const float var = (float)(s2 * inv_t - mean * mean);

    __syncthreads();

    const int t0 = B0 + threadIdx.x * CHUNK;     // first output index of this thread
    float h = var, q = var;
    float4* out4 = (float4*)(out + t0);

    if (blockIdx.x != 0) {
        // ---- uniform fast path: WARM steps from LDS, 2 float4 in flight ----
        const int dw = threadIdx.x * CHUNK;      // warm start dword in LDS
        float4 a = lds_r4(ybuf, dw + 0);
        float4 b = lds_r4(ybuf, dw + 4);
        #pragma unroll 2
        for (int f = 0; f < WARM / 4; f += 2) {
            float4 na = lds_r4(ybuf, dw + 4 * (f + 2));  // last iter: prefetch the emit data
            float4 nb = lds_r4(ybuf, dw + 4 * (f + 3));
            chn_step4(a, h, q, P);
            chn_step4(b, h, q, P);
            a = na; b = nb;
        }
        // a = y[t0..t0+3], b = y[t0+4..t0+7]
        float4 o;
        o.x = h; chn_step(a.x, h, q, P);
        o.y = h; chn_step(a.y, h, q, P);
        o.z = h; chn_step(a.z, h, q, P);
        o.w = h; chn_step(a.w, h, q, P);
        out4[0] = o;
        o.x = h; chn_step(b.x, h, q, P);
        o.y = h; chn_step(b.y, h, q, P);
        o.z = h; chn_step(b.z, h, q, P);
        o.w = h; chn_step(b.w, h, q, P);
        out4[1] = o;
    } else {
        // ---- block 0: exact ramp from t=0 (gbase==0, LDS dword == global idx) ----
        const int nW = (t0 < WARM) ? t0 : WARM;  // multiple of 8
        const int d0 = t0 - nW;
        for (int f = 0; f < nW / 4; ++f) {
            float4 v = lds_r4(ybuf, d0 + 4 * f);
            chn_step4(v, h, q, P);
        }
        #pragma unroll
        for (int j = 0; j < CHUNK / 4; ++j) {
            float4 v = lds_r4(ybuf, t0 + 4 * j);
            float4 o;
            o.x = h; chn_step(v.x, h, q, P);
            o.y = h; chn_step(v.y, h, q, P);
            o.z = h; chn_step(v.z, h, q, P);
            o.w = h; chn_step(v.w, h, q, P);
            out4[j] = o;
        }
    }
}

extern "C" void kernel_launch(void* const* d_in, const int* in_sizes, int n_in,
                              void* d_out, int out_size, void* d_ws, size_t ws_size,
                              hipStream_t stream) {
    const float* y = (const float*)d_in[0];
    float* out = (float*)d_out;
    double2* ws = (double2*)d_ws;   // 256 double2 partials = 4 KB

    var_partials_kernel<<<RGRID, 256, 0, stream>>>(y, ws);

    chn_scan_kernel<<<SGRID, SBLOCK, 0, stream>>>(
        y, out, ws,
        (const float*)d_in[1], (const float*)d_in[2], (const float*)d_in[3],
        (const float*)d_in[4], (const float*)d_in[5], (const float*)d_in[6],
        (const float*)d_in[7], (const float*)d_in[8]);
}

// Round 6
// 89.252 us; speedup vs baseline: 1.1983x; 1.0103x over previous
//
#include <hip/hip_runtime.h>

#define T_LEN   1048576
#define CHUNK   8                            // 8 outputs/thread -> 2 waves/SIMD
#define WARM    384                          // rho^384 ~ 2.6e-2 contraction of start-guess error
#define SBLOCK  256
#define OUTS_PER_BLOCK (SBLOCK * CHUNK)      // 2048
#define SGRID   (T_LEN / OUTS_PER_BLOCK)     // 512 blocks -> 2 blocks/CU
#define WIN     (WARM + OUTS_PER_BLOCK)      // 2432 floats per block window
#define WIN4    (WIN / 4)                    // 608 float4
#define LDS_DW  (WIN + (WIN / 64) * 4)       // pad +4 dwords per 64 -> 2584 dwords (10.3 KB)
#define RGRID   256

typedef float v2f __attribute__((ext_vector_type(2)));

// ---------------- Kernel A: per-block fp64 partial sums (no atomics) --------------
__global__ __launch_bounds__(256)
void var_partials_kernel(const float* __restrict__ y, double2* __restrict__ ws) {
    int tid = blockIdx.x * blockDim.x + threadIdx.x;
    const float4* y4 = (const float4*)y;
    const int stride = RGRID * 256;          // 65536
    float4 v0 = y4[tid];
    float4 v1 = y4[tid + stride];
    float4 v2 = y4[tid + 2 * stride];
    float4 v3 = y4[tid + 3 * stride];
    double s = 0.0, s2 = 0.0;
    #define ACC(v) { double a=(v).x,b=(v).y,c=(v).z,d=(v).w; s += (a+b)+(c+d); s2 += (a*a+b*b)+(c*c+d*d); }
    ACC(v0) ACC(v1) ACC(v2) ACC(v3)
    #undef ACC
    for (int off = 32; off >= 1; off >>= 1) {
        s  += __shfl_down(s,  off, 64);
        s2 += __shfl_down(s2, off, 64);
    }
    __shared__ double lsum[4], lsq[4];
    int lane = threadIdx.x & 63, wv = threadIdx.x >> 6;
    if (lane == 0) { lsum[wv] = s; lsq[wv] = s2; }
    __syncthreads();
    if (threadIdx.x == 0) {
        double2 o;
        o.x = (lsum[0] + lsum[1]) + (lsum[2] + lsum[3]);
        o.y = (lsq[0]  + lsq[1])  + (lsq[2]  + lsq[3]);
        ws[blockIdx.x] = o;
    }
}

// ---------------- Recurrence step, y-precomputed form ------------------------------
// Verified form: u=y-lam*h; r=1/h; t=u*u*r;
//   h' = DA + E*q + B*u + phi*h + A*t
//   q' = cV + rho*q + cv2*u + vphi*t
// Expand t = y^2*r - 2*lam*y + lam^2*h, u = y - lam*h:
//   h' = [DA + (B-2*A*lam)*y]    + E*q   + (phi - B*lam + A*lam^2)*h  + (A*y^2)*r
//   q' = [cV + (cv2-2*vphi*lam)*y] + rho*q + (vphi*lam^2 - cv2*lam)*h + (vphi*y^2)*r
// ky, yv depend ONLY on y -> precomputed in bulk, off the h-chain.
// In-loop: rcp + 3 v_pk_fma_f32. Chain: h -> rcp -> 1 fma.
struct ChnC { v2f G, DC, ER, PH, AV; };
struct Pre  { v2f ky, yv; };

__device__ __forceinline__ Pre mk_pre(float yv_, const ChnC& C) {
    Pre p;
    float y2 = yv_ * yv_;
    p.ky = __builtin_elementwise_fma(C.G, (v2f){yv_, yv_}, C.DC);
    p.yv = C.AV * (v2f){y2, y2};
    return p;
}

__device__ __forceinline__ void chn_step(const Pre& p, float& h, float& q, const ChnC& C) {
    float r = __builtin_amdgcn_rcpf(h);
    v2f m = __builtin_elementwise_fma(C.ER, (v2f){q, q}, p.ky);
    m     = __builtin_elementwise_fma(C.PH, (v2f){h, h}, m);
    m     = __builtin_elementwise_fma(p.yv, (v2f){r, r}, m);
    h = m.x;
    q = m.y;
}

// padded LDS index: +4 dwords per 64 (keeps 16B alignment of 4-aligned d)
__device__ __forceinline__ float4 lds_r4(const float* b, int d) {
    return *(const float4*)&b[d + ((d >> 6) << 2)];
}
__device__ __forceinline__ void lds_w4(float* b, int d, float4 v) {
    *(float4*)&b[d + ((d >> 6) << 2)] = v;
}

// ---------------- Kernel B: LDS-staged chunked scan --------------------------------
__global__ __launch_bounds__(SBLOCK)
void chn_scan_kernel(const float* __restrict__ y, float* __restrict__ out,
                     const double2* __restrict__ ws,
                     const float* __restrict__ p_omega, const float* __restrict__ p_alpha,
                     const float* __restrict__ p_phi,   const float* __restrict__ p_lam,
                     const float* __restrict__ p_gam1,  const float* __restrict__ p_gam2,
                     const float* __restrict__ p_vphi,  const float* __restrict__ p_rho) {
    __shared__ __align__(16) float ybuf[LDS_DW];

    const int B0    = blockIdx.x * OUTS_PER_BLOCK;
    const int gbase = (blockIdx.x == 0) ? 0 : (B0 - WARM);

    // ---- stage window into LDS, coalesced global float4 reads ----
    {
        const float4* g4 = (const float4*)(y + gbase);
        for (int i = threadIdx.x; i < WIN4; i += SBLOCK) {
            lds_w4(ybuf, 4 * i, g4[i]);
        }
    }

    // ---- constants (overlaps with staging loads) ----
    const float omega = *p_omega, alpha = *p_alpha, phi = *p_phi, lam = *p_lam;
    const float gam1 = *p_gam1, gam2 = *p_gam2, vphi = *p_vphi, rho = *p_rho;
    const float onemphi = 1.0f - phi;
    const float c0  = omega * (1.0f - rho);
    const float cv2 = -2.0f * gam2 * vphi;
    const float c1  = -2.0f * gam1 * alpha;
    const float A   = fmaf(onemphi, vphi, alpha);
    const float B   = fmaf(onemphi, cv2, c1);
    const float E   = onemphi * rho;
    ChnC C;
    C.G  = (v2f){B - 2.0f * A * lam,            cv2 - 2.0f * vphi * lam};
    C.DC = (v2f){onemphi * c0 - A,              c0 - vphi};
    C.ER = (v2f){E,                             rho};
    C.PH = (v2f){phi - B * lam + A * lam * lam, vphi * lam * lam - cv2 * lam};
    C.AV = (v2f){A,                             vphi};

    // ---- variance: wave-redundant reduce of 256 double2 partials ----
    int lane = threadIdx.x & 63;
    double s = 0.0, s2 = 0.0;
    #pragma unroll
    for (int k = 0; k < 4; ++k) {
        double2 v = ws[lane + 64 * k];
        s += v.x; s2 += v.y;
    }
    #pragma unroll
    for (int off = 32; off >= 1; off >>= 1) {
        s  += __shfl_xor(s,  off, 64);
        s2 += __shfl_xor(s2, off, 64);
    }
    const double inv_t = 1.0 / (double)T_LEN;
    double mean = s * inv_t;
    const float var = (float)(s2 * inv_t - mean * mean);

    __syncthreads();

    const int t0 = B0 + threadIdx.x * CHUNK;
    float h = var, q = var;
    float4* out4 = (float4*)(out + t0);

    if (blockIdx.x != 0) {
        // ---- uniform fast path: precompute-next-8 overlapped with step-current-8 ----
        const int dw = threadIdx.x * CHUNK;
        float4 a = lds_r4(ybuf, dw + 0);
        float4 b = lds_r4(ybuf, dw + 4);
        Pre pc[8];
        pc[0] = mk_pre(a.x, C); pc[1] = mk_pre(a.y, C);
        pc[2] = mk_pre(a.z, C); pc[3] = mk_pre(a.w, C);
        pc[4] = mk_pre(b.x, C); pc[5] = mk_pre(b.y, C);
        pc[6] = mk_pre(b.z, C); pc[7] = mk_pre(b.w, C);
        for (int f = 0; f < WARM / 4; f += 2) {
            // last iter loads dwords WARM..WARM+7 = y[t0..t0+7] (the emit inputs)
            float4 na = lds_r4(ybuf, dw + 4 * (f + 2));
            float4 nb = lds_r4(ybuf, dw + 4 * (f + 3));
            #pragma unroll
            for (int j = 0; j < 8; ++j) chn_step(pc[j], h, q, C);
            pc[0] = mk_pre(na.x, C); pc[1] = mk_pre(na.y, C);
            pc[2] = mk_pre(na.z, C); pc[3] = mk_pre(na.w, C);
            pc[4] = mk_pre(nb.x, C); pc[5] = mk_pre(nb.y, C);
            pc[6] = mk_pre(nb.z, C); pc[7] = mk_pre(nb.w, C);
        }
        // pc[] now holds y[t0..t0+7]
        float4 o;
        o.x = h; chn_step(pc[0], h, q, C);
        o.y = h; chn_step(pc[1], h, q, C);
        o.z = h; chn_step(pc[2], h, q, C);
        o.w = h; chn_step(pc[3], h, q, C);
        out4[0] = o;
        o.x = h; chn_step(pc[4], h, q, C);
        o.y = h; chn_step(pc[5], h, q, C);
        o.z = h; chn_step(pc[6], h, q, C);
        o.w = h; chn_step(pc[7], h, q, C);
        out4[1] = o;
    } else {
        // ---- block 0: exact ramp from t=0 (gbase==0, LDS dword == global idx) ----
        const int nW = (t0 < WARM) ? t0 : WARM;  // multiple of 8
        const int d0 = t0 - nW;
        for (int f = 0; f < nW / 4; ++f) {
            float4 v = lds_r4(ybuf, d0 + 4 * f);
            chn_step(mk_pre(v.x, C), h, q, C);
            chn_step(mk_pre(v.y, C), h, q, C);
            chn_step(mk_pre(v.z, C), h, q, C);
            chn_step(mk_pre(v.w, C), h, q, C);
        }
        #pragma unroll
        for (int j = 0; j < CHUNK / 4; ++j) {
            float4 v = lds_r4(ybuf, t0 + 4 * j);
            float4 o;
            o.x = h; chn_step(mk_pre(v.x, C), h, q, C);
            o.y = h; chn_step(mk_pre(v.y, C), h, q, C);
            o.z = h; chn_step(mk_pre(v.z, C), h, q, C);
            o.w = h; chn_step(mk_pre(v.w, C), h, q, C);
            out4[j] = o;
        }
    }
}

extern "C" void kernel_launch(void* const* d_in, const int* in_sizes, int n_in,
                              void* d_out, int out_size, void* d_ws, size_t ws_size,
                              hipStream_t stream) {
    const float* y = (const float*)d_in[0];
    float* out = (float*)d_out;
    double2* ws = (double2*)d_ws;   // 256 double2 partials = 4 KB

    var_partials_kernel<<<RGRID, 256, 0, stream>>>(y, ws);

    chn_scan_kernel<<<SGRID, SBLOCK, 0, stream>>>(
        y, out, ws,
        (const float*)d_in[1], (const float*)d_in[2], (const float*)d_in[3],
        (const float*)d_in[4], (const float*)d_in[5], (const float*)d_in[6],
        (const float*)d_in[7], (const float*)d_in[8]);
}

// Round 7
// 81.682 us; speedup vs baseline: 1.3093x; 1.0927x over previous
//
#include <hip/hip_runtime.h>

#define T_LEN   1048576
#define CHUNK   16                           // 16 outputs/thread -> 1 wave/SIMD, minimal warm overhead
#define WARM    256                          // rho^256 ~ 0.087; truncation ~3e-7 (abs floor is 9.5e-7)
#define SBLOCK  256
#define OUTS_PER_BLOCK (SBLOCK * CHUNK)      // 4096
#define SGRID   (T_LEN / OUTS_PER_BLOCK)     // 256 blocks -> 1 block/CU
#define WIN     (WARM + OUTS_PER_BLOCK)      // 4352 floats per block window
#define WIN4    (WIN / 4)                    // 1088 float4
#define LDS_DW  (WIN + (WIN / 64) * 4)       // +4 dwords pad per 64 -> 4624 dwords (18.5 KB)
#define RGRID   256

typedef float v2f __attribute__((ext_vector_type(2)));

// ---------------- Kernel A: per-block fp64 partial sums (no atomics) --------------
__global__ __launch_bounds__(256)
void var_partials_kernel(const float* __restrict__ y, double2* __restrict__ ws) {
    int tid = blockIdx.x * blockDim.x + threadIdx.x;
    const float4* y4 = (const float4*)y;
    const int stride = RGRID * 256;          // 65536
    float4 v0 = y4[tid];
    float4 v1 = y4[tid + stride];
    float4 v2 = y4[tid + 2 * stride];
    float4 v3 = y4[tid + 3 * stride];
    double s = 0.0, s2 = 0.0;
    #define ACC(v) { double a=(v).x,b=(v).y,c=(v).z,d=(v).w; s += (a+b)+(c+d); s2 += (a*a+b*b)+(c*c+d*d); }
    ACC(v0) ACC(v1) ACC(v2) ACC(v3)
    #undef ACC
    for (int off = 32; off >= 1; off >>= 1) {
        s  += __shfl_down(s,  off, 64);
        s2 += __shfl_down(s2, off, 64);
    }
    __shared__ double lsum[4], lsq[4];
    int lane = threadIdx.x & 63, wv = threadIdx.x >> 6;
    if (lane == 0) { lsum[wv] = s; lsq[wv] = s2; }
    __syncthreads();
    if (threadIdx.x == 0) {
        double2 o;
        o.x = (lsum[0] + lsum[1]) + (lsum[2] + lsum[3]);
        o.y = (lsq[0]  + lsq[1])  + (lsq[2]  + lsq[3]);
        ws[blockIdx.x] = o;
    }
}

// ---------------- Recurrence step, y-precomputed + bit-magic reciprocal ------------
// h' = ky_h + E*q + PH_h*h + (A*y^2)  * (1/h)
// q' = ky_q + rho*q + PH_q*h + (v*y^2)* (1/h)
// 1/h via exponent-flip seed (<=5% err, valid for all positive floats, no divergence
// risk since seed comes from h itself) + 1 Newton -> <=0.4% rel err. Error on h':
// (A*y^2/h)*0.4% <= ~3e-7 worst tail, << 7.5e-6 budget. Chain per step:
// h -> int_sub -> fma -> mul -> pk_fma = 4 fast-VALU latencies (no trans pipe).
struct ChnC { v2f G, DC, ER, PH, AV; };
struct Pre  { v2f ky, yv; };

__device__ __forceinline__ Pre mk_pre(float yv_, const ChnC& C) {
    Pre p;
    float y2 = yv_ * yv_;
    p.ky = __builtin_elementwise_fma(C.G, (v2f){yv_, yv_}, C.DC);
    p.yv = C.AV * (v2f){y2, y2};
    return p;
}

__device__ __forceinline__ void chn_step(const Pre& p, float& h, float& q, const ChnC& C) {
    float r0 = __uint_as_float(0x7EF311C3u - __float_as_uint(h));  // ~5% approx of 1/h
    float e  = fmaf(-h, r0, 2.0f);                                  // Newton residual
    float r  = r0 * e;                                              // <=0.4% rel err
    v2f m = __builtin_elementwise_fma(C.ER, (v2f){q, q}, p.ky);
    m     = __builtin_elementwise_fma(C.PH, (v2f){h, h}, m);
    m     = __builtin_elementwise_fma(p.yv, (v2f){r, r}, m);
    h = m.x;
    q = m.y;
}

// padded LDS index: +4 dwords per 64 (keeps 16B alignment of 4-aligned d)
__device__ __forceinline__ float4 lds_r4(const float* b, int d) {
    return *(const float4*)&b[d + ((d >> 6) << 2)];
}
__device__ __forceinline__ void lds_w4(float* b, int d, float4 v) {
    *(float4*)&b[d + ((d >> 6) << 2)] = v;
}

// ---------------- Kernel B: LDS-staged chunked scan --------------------------------
__global__ __launch_bounds__(SBLOCK)
void chn_scan_kernel(const float* __restrict__ y, float* __restrict__ out,
                     const double2* __restrict__ ws,
                     const float* __restrict__ p_omega, const float* __restrict__ p_alpha,
                     const float* __restrict__ p_phi,   const float* __restrict__ p_lam,
                     const float* __restrict__ p_gam1,  const float* __restrict__ p_gam2,
                     const float* __restrict__ p_vphi,  const float* __restrict__ p_rho) {
    __shared__ __align__(16) float ybuf[LDS_DW];

    const int B0    = blockIdx.x * OUTS_PER_BLOCK;
    const int gbase = (blockIdx.x == 0) ? 0 : (B0 - WARM);

    // ---- stage window into LDS, coalesced global float4 reads ----
    {
        const float4* g4 = (const float4*)(y + gbase);
        for (int i = threadIdx.x; i < WIN4; i += SBLOCK) {
            lds_w4(ybuf, 4 * i, g4[i]);
        }
    }

    // ---- constants (overlaps with staging loads) ----
    const float omega = *p_omega, alpha = *p_alpha, phi = *p_phi, lam = *p_lam;
    const float gam1 = *p_gam1, gam2 = *p_gam2, vphi = *p_vphi, rho = *p_rho;
    const float onemphi = 1.0f - phi;
    const float c0  = omega * (1.0f - rho);
    const float cv2 = -2.0f * gam2 * vphi;
    const float c1  = -2.0f * gam1 * alpha;
    const float A   = fmaf(onemphi, vphi, alpha);
    const float B   = fmaf(onemphi, cv2, c1);
    const float E   = onemphi * rho;
    ChnC C;
    C.G  = (v2f){B - 2.0f * A * lam,            cv2 - 2.0f * vphi * lam};
    C.DC = (v2f){onemphi * c0 - A,              c0 - vphi};
    C.ER = (v2f){E,                             rho};
    C.PH = (v2f){phi - B * lam + A * lam * lam, vphi * lam * lam - cv2 * lam};
    C.AV = (v2f){A,                             vphi};

    // ---- variance: wave-redundant reduce of 256 double2 partials ----
    int lane = threadIdx.x & 63;
    double s = 0.0, s2 = 0.0;
    #pragma unroll
    for (int k = 0; k < 4; ++k) {
        double2 v = ws[lane + 64 * k];
        s += v.x; s2 += v.y;
    }
    #pragma unroll
    for (int off = 32; off >= 1; off >>= 1) {
        s  += __shfl_xor(s,  off, 64);
        s2 += __shfl_xor(s2, off, 64);
    }
    const double inv_t = 1.0 / (double)T_LEN;
    double mean = s * inv_t;
    const float var = (float)(s2 * inv_t - mean * mean);

    __syncthreads();

    const int t0 = B0 + threadIdx.x * CHUNK;
    float h = var, q = var;
    float4* out4 = (float4*)(out + t0);

    if (blockIdx.x != 0) {
        // ---- uniform fast path: WARM steps, precompute-next-8 overlap ----
        const int dw = threadIdx.x * CHUNK;
        float4 a = lds_r4(ybuf, dw + 0);
        float4 b = lds_r4(ybuf, dw + 4);
        Pre pc[8];
        pc[0] = mk_pre(a.x, C); pc[1] = mk_pre(a.y, C);
        pc[2] = mk_pre(a.z, C); pc[3] = mk_pre(a.w, C);
        pc[4] = mk_pre(b.x, C); pc[5] = mk_pre(b.y, C);
        pc[6] = mk_pre(b.z, C); pc[7] = mk_pre(b.w, C);
        for (int f = 0; f < WARM / 4; f += 2) {
            // last iter loads dwords WARM..WARM+7 = y[t0..t0+7] (the emit inputs)
            float4 na = lds_r4(ybuf, dw + 4 * (f + 2));
            float4 nb = lds_r4(ybuf, dw + 4 * (f + 3));
            #pragma unroll
            for (int j = 0; j < 8; ++j) chn_step(pc[j], h, q, C);
            pc[0] = mk_pre(na.x, C); pc[1] = mk_pre(na.y, C);
            pc[2] = mk_pre(na.z, C); pc[3] = mk_pre(na.w, C);
            pc[4] = mk_pre(nb.x, C); pc[5] = mk_pre(nb.y, C);
            pc[6] = mk_pre(nb.z, C); pc[7] = mk_pre(nb.w, C);
        }
        // pc[] holds y[t0..t0+7]; fetch y[t0+8..t0+15]
        float4 c = lds_r4(ybuf, dw + WARM + 8);
        float4 d = lds_r4(ybuf, dw + WARM + 12);
        float4 o;
        o.x = h; chn_step(pc[0], h, q, C);
        o.y = h; chn_step(pc[1], h, q, C);
        o.z = h; chn_step(pc[2], h, q, C);
        o.w = h; chn_step(pc[3], h, q, C);
        out4[0] = o;
        o.x = h; chn_step(pc[4], h, q, C);
        o.y = h; chn_step(pc[5], h, q, C);
        o.z = h; chn_step(pc[6], h, q, C);
        o.w = h; chn_step(pc[7], h, q, C);
        out4[1] = o;
        o.x = h; chn_step(mk_pre(c.x, C), h, q, C);
        o.y = h; chn_step(mk_pre(c.y, C), h, q, C);
        o.z = h; chn_step(mk_pre(c.z, C), h, q, C);
        o.w = h; chn_step(mk_pre(c.w, C), h, q, C);
        out4[2] = o;
        o.x = h; chn_step(mk_pre(d.x, C), h, q, C);
        o.y = h; chn_step(mk_pre(d.y, C), h, q, C);
        o.z = h; chn_step(mk_pre(d.z, C), h, q, C);
        o.w = h; chn_step(mk_pre(d.w, C), h, q, C);
        out4[3] = o;
    } else {
        // ---- block 0: exact ramp from t=0 (gbase==0, LDS dword == global idx) ----
        const int nW = (t0 < WARM) ? t0 : WARM;  // multiple of 16
        const int d0 = t0 - nW;
        for (int f = 0; f < nW / 4; ++f) {
            float4 v = lds_r4(ybuf, d0 + 4 * f);
            chn_step(mk_pre(v.x, C), h, q, C);
            chn_step(mk_pre(v.y, C), h, q, C);
            chn_step(mk_pre(v.z, C), h, q, C);
            chn_step(mk_pre(v.w, C), h, q, C);
        }
        #pragma unroll
        for (int j = 0; j < CHUNK / 4; ++j) {
            float4 v = lds_r4(ybuf, t0 + 4 * j);
            float4 o;
            o.x = h; chn_step(mk_pre(v.x, C), h, q, C);
            o.y = h; chn_step(mk_pre(v.y, C), h, q, C);
            o.z = h; chn_step(mk_pre(v.z, C), h, q, C);
            o.w = h; chn_step(mk_pre(v.w, C), h, q, C);
            out4[j] = o;
        }
    }
}

extern "C" void kernel_launch(void* const* d_in, const int* in_sizes, int n_in,
                              void* d_out, int out_size, void* d_ws, size_t ws_size,
                              hipStream_t stream) {
    const float* y = (const float*)d_in[0];
    float* out = (float*)d_out;
    double2* ws = (double2*)d_ws;   // 256 double2 partials = 4 KB

    var_partials_kernel<<<RGRID, 256, 0, stream>>>(y, ws);

    chn_scan_kernel<<<SGRID, SBLOCK, 0, stream>>>(
        y, out, ws,
        (const float*)d_in[1], (const float*)d_in[2], (const float*)d_in[3],
        (const float*)d_in[4], (const float*)d_in[5], (const float*)d_in[6],
        (const float*)d_in[7], (const float*)d_in[8]);
}